// Round 1
// baseline (648.149 us; speedup 1.0000x reference)
//
#include <hip/hip_runtime.h>
#include <hip/hip_bf16.h>

// GAT-style graph attention, fp32.
// N=50000 nodes, E=600000 edges, FEAT=128, H=8 heads, D=16.
// Pipeline:
//  0. transpose Wq/Wk/Wv/Wo to k-major (coalesced GEMM loads)
//  1. fused QKV GEMM (X @ W^T + b), X tile in LDS, WT loads coalesced
//  2. per-(edge,head) scores = dot(q[src,h],k[dest,h])/4 + atomicMax segmax[src,h]
//  3. exp(score - segmax) + atomicAdd segsum[src,h]
//  4. normalize weights
//  5. scatter: agg[dest] += v[src]*w  (fp32 global atomics, coalesced per wave)
//  6. out = agg @ Wo^T + bo

#define FEAT 128
#define NHEAD 8
#define HDIM 16

// ---- ordered-uint encoding for float atomicMax (init 0 < every finite enc) ----
__device__ __forceinline__ unsigned enc_f(float f) {
    unsigned b = __float_as_uint(f);
    return (b & 0x80000000u) ? ~b : (b | 0x80000000u);
}
__device__ __forceinline__ float dec_f(unsigned k) {
    return (k & 0x80000000u) ? __uint_as_float(k ^ 0x80000000u) : __uint_as_float(~k);
}

// ---- 0: transpose 4 weight matrices into WT[m][k*128+f]  (W is [f][k]) ----
__global__ __launch_bounds__(256) void transpose_w_kernel(
    const float* __restrict__ Wq, const float* __restrict__ Wk,
    const float* __restrict__ Wv, const float* __restrict__ Wo,
    float* __restrict__ WT)
{
    int tid = blockIdx.x * 256 + threadIdx.x;   // 4*16384 total
    int m = tid >> 14;
    int idx = tid & 16383;
    int r = idx >> 7;      // f
    int c = idx & 127;     // k
    const float* W = (m == 0) ? Wq : (m == 1) ? Wk : (m == 2) ? Wv : Wo;
    WT[m * 16384 + c * 128 + r] = W[r * 128 + c];
}

// ---- 1: fused QKV GEMM.  block = 256 threads, 32 nodes/block ----
#define QKV_NPB 32
__global__ __launch_bounds__(256) void qkv_kernel(
    const float* __restrict__ X, const float* __restrict__ WT,
    const float* __restrict__ bq, const float* __restrict__ bk, const float* __restrict__ bv,
    float* __restrict__ Q, float* __restrict__ K, float* __restrict__ V, int N)
{
    __shared__ float xs[QKV_NPB * FEAT];
    const int n0 = blockIdx.x * QKV_NPB;
    const int tid = threadIdx.x;

    // stage X tile (float4, coalesced)
    {
        const float4* Xv = (const float4*)(X + (size_t)n0 * FEAT);
        float4* xsv = (float4*)xs;
        int maxv = (min(QKV_NPB, N - n0)) * (FEAT / 4);
        #pragma unroll
        for (int i = 0; i < QKV_NPB * FEAT / 4 / 256; i++) {
            int idx = tid + i * 256;
            if (idx < maxv) xsv[idx] = Xv[idx];
        }
    }
    __syncthreads();

    const int fg = (tid & 31) * 4;   // feature base (0..124)
    const int ns = tid >> 5;         // node slot 0..7 (handles ns, ns+8, ns+16, ns+24)

    float4 a0[4], a1[4], a2[4];
    {
        float4 b0 = *(const float4*)(bq + fg);
        float4 b1 = *(const float4*)(bk + fg);
        float4 b2 = *(const float4*)(bv + fg);
        #pragma unroll
        for (int j = 0; j < 4; j++) { a0[j] = b0; a1[j] = b1; a2[j] = b2; }
    }
    const float* W0 = WT;            // Wq^T
    const float* W1 = WT + 16384;    // Wk^T
    const float* W2 = WT + 32768;    // Wv^T

    const float* x0 = xs + (ns + 0) * FEAT;
    const float* x1 = xs + (ns + 8) * FEAT;
    const float* x2 = xs + (ns + 16) * FEAT;
    const float* x3 = xs + (ns + 24) * FEAT;

    #pragma unroll 2
    for (int k = 0; k < FEAT; k++) {
        float4 w0 = *(const float4*)(W0 + k * 128 + fg);
        float4 w1 = *(const float4*)(W1 + k * 128 + fg);
        float4 w2 = *(const float4*)(W2 + k * 128 + fg);
        float xv[4] = { x0[k], x1[k], x2[k], x3[k] };
        #pragma unroll
        for (int j = 0; j < 4; j++) {
            float x = xv[j];
            a0[j].x += x * w0.x; a0[j].y += x * w0.y; a0[j].z += x * w0.z; a0[j].w += x * w0.w;
            a1[j].x += x * w1.x; a1[j].y += x * w1.y; a1[j].z += x * w1.z; a1[j].w += x * w1.w;
            a2[j].x += x * w2.x; a2[j].y += x * w2.y; a2[j].z += x * w2.z; a2[j].w += x * w2.w;
        }
    }
    #pragma unroll
    for (int j = 0; j < 4; j++) {
        int n = n0 + ns + j * 8;
        if (n < N) {
            *(float4*)(Q + (size_t)n * FEAT + fg) = a0[j];
            *(float4*)(K + (size_t)n * FEAT + fg) = a1[j];
            *(float4*)(V + (size_t)n * FEAT + fg) = a2[j];
        }
    }
}

// ---- 2: per-(edge,head) scores + segment max ----
__global__ __launch_bounds__(256) void scores_kernel(
    const int* __restrict__ srcs, const int* __restrict__ dsts,
    const float* __restrict__ Q, const float* __restrict__ K,
    float* __restrict__ scores, unsigned* __restrict__ segmax, int E)
{
    int tid = blockIdx.x * 256 + threadIdx.x;
    if (tid >= E * NHEAD) return;
    int e = tid >> 3, h = tid & 7;
    int s = srcs[e], d = dsts[e];
    const float4* qp = (const float4*)(Q + (size_t)s * FEAT + h * HDIM);
    const float4* kp = (const float4*)(K + (size_t)d * FEAT + h * HDIM);
    float acc = 0.f;
    #pragma unroll
    for (int i = 0; i < 4; i++) {
        float4 q4 = qp[i], k4 = kp[i];
        acc += q4.x * k4.x + q4.y * k4.y + q4.z * k4.z + q4.w * k4.w;
    }
    float sc = acc * 0.25f;   // 1/sqrt(16)
    scores[tid] = sc;
    atomicMax(segmax + s * NHEAD + h, enc_f(sc));
}

// ---- 3: exp(score - max) + segment sum ----
__global__ __launch_bounds__(256) void expsum_kernel(
    const int* __restrict__ srcs, float* __restrict__ scores,
    const unsigned* __restrict__ segmax, float* __restrict__ segsum, int E)
{
    int tid = blockIdx.x * 256 + threadIdx.x;
    if (tid >= E * NHEAD) return;
    int e = tid >> 3, h = tid & 7;
    int s = srcs[e];
    float m = dec_f(segmax[s * NHEAD + h]);
    float w = expf(scores[tid] - m);
    scores[tid] = w;
    atomicAdd(segsum + s * NHEAD + h, w);
}

// ---- 4: normalize weights in place ----
__global__ __launch_bounds__(256) void normalize_kernel(
    const int* __restrict__ srcs, float* __restrict__ scores,
    const float* __restrict__ segsum, int E)
{
    int tid = blockIdx.x * 256 + threadIdx.x;
    if (tid >= E * NHEAD) return;
    int e = tid >> 3, h = tid & 7;
    int s = srcs[e];
    scores[tid] = scores[tid] / segsum[s * NHEAD + h];
}

// ---- 5: scatter-add aggregation: agg[dest] += v[src]*w ----
__global__ __launch_bounds__(256) void aggregate_kernel(
    const int* __restrict__ srcs, const int* __restrict__ dsts,
    const float* __restrict__ V, const float* __restrict__ weights,
    float* __restrict__ agg, int E)
{
    int tid = blockIdx.x * 256 + threadIdx.x;
    if (tid >= E * FEAT) return;
    int e = tid >> 7, c = tid & 127;
    int h = c >> 4;
    int s = srcs[e], d = dsts[e];
    float wt = weights[e * NHEAD + h];
    float val = V[(size_t)s * FEAT + c] * wt;
    atomicAdd(agg + (size_t)d * FEAT + c, val);
}

// ---- 6: output GEMM: out = agg @ Wo^T + bo ----
__global__ __launch_bounds__(256) void out_kernel(
    const float* __restrict__ A, const float* __restrict__ WoT,
    const float* __restrict__ bo, float* __restrict__ out, int N)
{
    __shared__ float xs[QKV_NPB * FEAT];
    const int n0 = blockIdx.x * QKV_NPB;
    const int tid = threadIdx.x;
    {
        const float4* Av = (const float4*)(A + (size_t)n0 * FEAT);
        float4* xsv = (float4*)xs;
        int maxv = (min(QKV_NPB, N - n0)) * (FEAT / 4);
        #pragma unroll
        for (int i = 0; i < QKV_NPB * FEAT / 4 / 256; i++) {
            int idx = tid + i * 256;
            if (idx < maxv) xsv[idx] = Av[idx];
        }
    }
    __syncthreads();

    const int fg = (tid & 31) * 4;
    const int ns = tid >> 5;
    float4 a0[4];
    {
        float4 b0 = *(const float4*)(bo + fg);
        #pragma unroll
        for (int j = 0; j < 4; j++) a0[j] = b0;
    }
    const float* x0 = xs + (ns + 0) * FEAT;
    const float* x1 = xs + (ns + 8) * FEAT;
    const float* x2 = xs + (ns + 16) * FEAT;
    const float* x3 = xs + (ns + 24) * FEAT;

    #pragma unroll 2
    for (int k = 0; k < FEAT; k++) {
        float4 w0 = *(const float4*)(WoT + k * 128 + fg);
        float xv[4] = { x0[k], x1[k], x2[k], x3[k] };
        #pragma unroll
        for (int j = 0; j < 4; j++) {
            float x = xv[j];
            a0[j].x += x * w0.x; a0[j].y += x * w0.y; a0[j].z += x * w0.z; a0[j].w += x * w0.w;
        }
    }
    #pragma unroll
    for (int j = 0; j < 4; j++) {
        int n = n0 + ns + j * 8;
        if (n < N) *(float4*)(out + (size_t)n * FEAT + fg) = a0[j];
    }
}

extern "C" void kernel_launch(void* const* d_in, const int* in_sizes, int n_in,
                              void* d_out, int out_size, void* d_ws, size_t ws_size,
                              hipStream_t stream) {
    const float* X  = (const float*)d_in[0];
    const int*   ei = (const int*)d_in[1];
    const float* Wq = (const float*)d_in[2];
    const float* bq = (const float*)d_in[3];
    const float* Wk = (const float*)d_in[4];
    const float* bk = (const float*)d_in[5];
    const float* Wv = (const float*)d_in[6];
    const float* bv = (const float*)d_in[7];
    const float* Wo = (const float*)d_in[8];
    const float* bo = (const float*)d_in[9];
    float* out = (float*)d_out;

    const int N = in_sizes[0] / FEAT;        // 50000
    const int E = in_sizes[1] / 2;           // 600000
    const int* srcs = ei;
    const int* dsts = ei + E;

    // workspace layout (floats); agg aliases Q (Q dead after scores pass)
    float* ws = (float*)d_ws;
    float*    WT     = ws;                                // 4*16384
    float*    Kb     = WT + 4 * 16384;                    // N*FEAT
    float*    Vb     = Kb + (size_t)N * FEAT;             // N*FEAT
    float*    scores = Vb + (size_t)N * FEAT;             // E*NHEAD
    unsigned* segmax = (unsigned*)(scores + (size_t)E * NHEAD); // N*NHEAD
    float*    segsum = (float*)segmax + (size_t)N * NHEAD;      // N*NHEAD
    float*    Qb     = segsum + (size_t)N * NHEAD;        // N*FEAT (also agg)
    float*    agg    = Qb;

    // zero segmax + segsum (contiguous)
    hipMemsetAsync(segmax, 0, (size_t)N * NHEAD * 2 * sizeof(float), stream);

    transpose_w_kernel<<<(4 * 16384) / 256, 256, 0, stream>>>(Wq, Wk, Wv, Wo, WT);

    qkv_kernel<<<(N + QKV_NPB - 1) / QKV_NPB, 256, 0, stream>>>(
        X, WT, bq, bk, bv, Qb, Kb, Vb, N);

    int eh_blocks = (E * NHEAD + 255) / 256;
    scores_kernel<<<eh_blocks, 256, 0, stream>>>(srcs, dsts, Qb, Kb, scores, segmax, E);

    // zero agg region (Q is dead now)
    hipMemsetAsync(agg, 0, (size_t)N * FEAT * sizeof(float), stream);

    expsum_kernel<<<eh_blocks, 256, 0, stream>>>(srcs, scores, segmax, segsum, E);
    normalize_kernel<<<eh_blocks, 256, 0, stream>>>(srcs, scores, segsum, E);

    int ef_blocks = (int)(((size_t)E * FEAT + 255) / 256);
    aggregate_kernel<<<ef_blocks, 256, 0, stream>>>(srcs, dsts, Vb, scores, agg, E);

    out_kernel<<<(N + QKV_NPB - 1) / QKV_NPB, 256, 0, stream>>>(agg, WT + 3 * 16384, bo, out, N);
}

// Round 2
// 507.487 us; speedup vs baseline: 1.2772x; 1.2772x over previous
//
#include <hip/hip_runtime.h>
#include <hip/hip_bf16.h>

// GAT-style graph attention, fp32. N=50000, E=600000, FEAT=128, H=8, D=16.
// R2: CSR-by-dest gather aggregation (no fp32 atomics in heavy pass),
//     fused scores+exp+segsum, normalization folded into gather,
//     out-GEMM in-place on d_out.

#define FEAT 128
#define NHEAD 8
#define HDIM 16

// ---- 0: transpose 4 weight matrices into WT[m][k*128+f]  (W is [f][k]) ----
__global__ __launch_bounds__(256) void transpose_w_kernel(
    const float* __restrict__ Wq, const float* __restrict__ Wk,
    const float* __restrict__ Wv, const float* __restrict__ Wo,
    float* __restrict__ WT)
{
    int tid = blockIdx.x * 256 + threadIdx.x;   // 4*16384 total
    int m = tid >> 14;
    int idx = tid & 16383;
    int r = idx >> 7;      // f
    int c = idx & 127;     // k
    const float* W = (m == 0) ? Wq : (m == 1) ? Wk : (m == 2) ? Wv : Wo;
    WT[m * 16384 + c * 128 + r] = W[r * 128 + c];
}

// ---- 1: fused QKV GEMM.  block = 256 threads, 32 nodes/block ----
#define QKV_NPB 32
__global__ __launch_bounds__(256) void qkv_kernel(
    const float* __restrict__ X, const float* __restrict__ WT,
    const float* __restrict__ bq, const float* __restrict__ bk, const float* __restrict__ bv,
    float* __restrict__ Q, float* __restrict__ K, float* __restrict__ V, int N)
{
    __shared__ float xs[QKV_NPB * FEAT];
    const int n0 = blockIdx.x * QKV_NPB;
    const int tid = threadIdx.x;
    {
        const float4* Xv = (const float4*)(X + (size_t)n0 * FEAT);
        float4* xsv = (float4*)xs;
        int maxv = (min(QKV_NPB, N - n0)) * (FEAT / 4);
        #pragma unroll
        for (int i = 0; i < QKV_NPB * FEAT / 4 / 256; i++) {
            int idx = tid + i * 256;
            if (idx < maxv) xsv[idx] = Xv[idx];
        }
    }
    __syncthreads();

    const int fg = (tid & 31) * 4;
    const int ns = tid >> 5;

    float4 a0[4], a1[4], a2[4];
    {
        float4 b0 = *(const float4*)(bq + fg);
        float4 b1 = *(const float4*)(bk + fg);
        float4 b2 = *(const float4*)(bv + fg);
        #pragma unroll
        for (int j = 0; j < 4; j++) { a0[j] = b0; a1[j] = b1; a2[j] = b2; }
    }
    const float* W0 = WT;
    const float* W1 = WT + 16384;
    const float* W2 = WT + 32768;

    const float* x0 = xs + (ns + 0) * FEAT;
    const float* x1 = xs + (ns + 8) * FEAT;
    const float* x2 = xs + (ns + 16) * FEAT;
    const float* x3 = xs + (ns + 24) * FEAT;

    #pragma unroll 2
    for (int k = 0; k < FEAT; k++) {
        float4 w0 = *(const float4*)(W0 + k * 128 + fg);
        float4 w1 = *(const float4*)(W1 + k * 128 + fg);
        float4 w2 = *(const float4*)(W2 + k * 128 + fg);
        float xv[4] = { x0[k], x1[k], x2[k], x3[k] };
        #pragma unroll
        for (int j = 0; j < 4; j++) {
            float x = xv[j];
            a0[j].x += x * w0.x; a0[j].y += x * w0.y; a0[j].z += x * w0.z; a0[j].w += x * w0.w;
            a1[j].x += x * w1.x; a1[j].y += x * w1.y; a1[j].z += x * w1.z; a1[j].w += x * w1.w;
            a2[j].x += x * w2.x; a2[j].y += x * w2.y; a2[j].z += x * w2.z; a2[j].w += x * w2.w;
        }
    }
    #pragma unroll
    for (int j = 0; j < 4; j++) {
        int n = n0 + ns + j * 8;
        if (n < N) {
            *(float4*)(Q + (size_t)n * FEAT + fg) = a0[j];
            *(float4*)(K + (size_t)n * FEAT + fg) = a1[j];
            *(float4*)(V + (size_t)n * FEAT + fg) = a2[j];
        }
    }
}

// ---- 2: fused scores + exp + segment-sum (no max pass: |score| <~ 6) ----
__global__ __launch_bounds__(256) void scores_kernel(
    const int* __restrict__ srcs, const int* __restrict__ dsts,
    const float* __restrict__ Q, const float* __restrict__ K,
    float* __restrict__ scores, float* __restrict__ segsum, int E)
{
    int tid = blockIdx.x * 256 + threadIdx.x;
    if (tid >= E * NHEAD) return;
    int e = tid >> 3, h = tid & 7;
    int s = srcs[e], d = dsts[e];
    const float4* qp = (const float4*)(Q + (size_t)s * FEAT + h * HDIM);
    const float4* kp = (const float4*)(K + (size_t)d * FEAT + h * HDIM);
    float acc = 0.f;
    #pragma unroll
    for (int i = 0; i < 4; i++) {
        float4 q4 = qp[i], k4 = kp[i];
        acc += q4.x * k4.x + q4.y * k4.y + q4.z * k4.z + q4.w * k4.w;
    }
    float w = expf(acc * 0.25f);   // 1/sqrt(16)
    scores[tid] = w;
    atomicAdd(segsum + s * NHEAD + h, w);
}

// ---- 3: in-place reciprocal of segsum ----
__global__ __launch_bounds__(256) void recip_kernel(float* __restrict__ segsum, int n)
{
    int i = blockIdx.x * 256 + threadIdx.x;
    if (i < n) segsum[i] = 1.0f / segsum[i];
}

// ---- 4: histogram of dests ----
__global__ __launch_bounds__(256) void hist_kernel(
    const int* __restrict__ dsts, int* __restrict__ counts, int E)
{
    int e = blockIdx.x * 256 + threadIdx.x;
    if (e < E) atomicAdd(counts + dsts[e], 1);
}

// ---- 5: two-level exclusive scan (196 blocks of 256) ----
__global__ __launch_bounds__(256) void scan1_kernel(
    const int* __restrict__ counts, int* __restrict__ offsets,
    int* __restrict__ blocksums, int N)
{
    __shared__ int buf[256];
    int t = threadIdx.x, i = blockIdx.x * 256 + t;
    int v = (i < N) ? counts[i] : 0;
    buf[t] = v; __syncthreads();
    int x = v;
    #pragma unroll
    for (int off = 1; off < 256; off <<= 1) {
        int y = (t >= off) ? buf[t - off] : 0;
        __syncthreads();
        x += y; buf[t] = x;
        __syncthreads();
    }
    if (i < N) offsets[i] = x - v;       // exclusive within block
    if (t == 255) blocksums[blockIdx.x] = x;
}

__global__ __launch_bounds__(256) void scan2_kernel(
    int* __restrict__ blocksums, int* __restrict__ blockoffs, int NB)
{
    __shared__ int buf[256];
    int t = threadIdx.x;
    int v = (t < NB) ? blocksums[t] : 0;
    buf[t] = v; __syncthreads();
    int x = v;
    #pragma unroll
    for (int off = 1; off < 256; off <<= 1) {
        int y = (t >= off) ? buf[t - off] : 0;
        __syncthreads();
        x += y; buf[t] = x;
        __syncthreads();
    }
    if (t < NB) blockoffs[t] = x - v;
}

__global__ __launch_bounds__(256) void scan3_kernel(
    int* __restrict__ offsets, const int* __restrict__ blockoffs,
    int* __restrict__ cursor, int N)
{
    int i = blockIdx.x * 256 + threadIdx.x;
    if (i < N) {
        int o = offsets[i] + blockoffs[blockIdx.x];
        offsets[i] = o;
        cursor[i] = o;
    }
}

// ---- 6: fill edge-id list bucketed by dest ----
__global__ __launch_bounds__(256) void fill_kernel(
    const int* __restrict__ dsts, int* __restrict__ cursor,
    int* __restrict__ eid, int E)
{
    int e = blockIdx.x * 256 + threadIdx.x;
    if (e < E) {
        int d = dsts[e];
        int pos = atomicAdd(cursor + d, 1);
        eid[pos] = e;
    }
}

// ---- 7: gather-aggregate, one wave per dest node, 2 cols/lane ----
#define GATH_WPB 4
__global__ __launch_bounds__(256) void gather_kernel(
    const int* __restrict__ offsets, const int* __restrict__ counts,
    const int* __restrict__ eid, const int* __restrict__ srcs,
    const float* __restrict__ V, const float* __restrict__ scores,
    const float* __restrict__ rsegsum, float* __restrict__ agg, int N)
{
    int wave = blockIdx.x * GATH_WPB + (threadIdx.x >> 6);
    if (wave >= N) return;
    int lane = threadIdx.x & 63;
    int h = lane >> 3;                       // head of cols 2*lane, 2*lane+1
    int start = offsets[wave], deg = counts[wave];
    float2 acc = {0.f, 0.f};
    for (int j = 0; j < deg; j++) {
        int e = eid[start + j];
        int s = srcs[e];
        float w = scores[(size_t)e * NHEAD + h] * rsegsum[(size_t)s * NHEAD + h];
        float2 v2 = *(const float2*)(V + (size_t)s * FEAT + lane * 2);
        acc.x += w * v2.x;
        acc.y += w * v2.y;
    }
    *(float2*)(agg + (size_t)wave * FEAT + lane * 2) = acc;
}

// ---- 8: out-GEMM, IN PLACE on d_out (each block stages its own rows) ----
__global__ __launch_bounds__(256) void out_kernel(
    float* __restrict__ A, const float* __restrict__ WoT,
    const float* __restrict__ bo, int N)
{
    __shared__ float xs[QKV_NPB * FEAT];
    const int n0 = blockIdx.x * QKV_NPB;
    const int tid = threadIdx.x;
    {
        const float4* Av = (const float4*)(A + (size_t)n0 * FEAT);
        float4* xsv = (float4*)xs;
        int maxv = (min(QKV_NPB, N - n0)) * (FEAT / 4);
        #pragma unroll
        for (int i = 0; i < QKV_NPB * FEAT / 4 / 256; i++) {
            int idx = tid + i * 256;
            if (idx < maxv) xsv[idx] = Av[idx];
        }
    }
    __syncthreads();

    const int fg = (tid & 31) * 4;
    const int ns = tid >> 5;
    float4 a0[4];
    {
        float4 b0 = *(const float4*)(bo + fg);
        #pragma unroll
        for (int j = 0; j < 4; j++) a0[j] = b0;
    }
    const float* x0 = xs + (ns + 0) * FEAT;
    const float* x1 = xs + (ns + 8) * FEAT;
    const float* x2 = xs + (ns + 16) * FEAT;
    const float* x3 = xs + (ns + 24) * FEAT;

    #pragma unroll 2
    for (int k = 0; k < FEAT; k++) {
        float4 w0 = *(const float4*)(WoT + k * 128 + fg);
        float xv[4] = { x0[k], x1[k], x2[k], x3[k] };
        #pragma unroll
        for (int j = 0; j < 4; j++) {
            float x = xv[j];
            a0[j].x += x * w0.x; a0[j].y += x * w0.y; a0[j].z += x * w0.z; a0[j].w += x * w0.w;
        }
    }
    #pragma unroll
    for (int j = 0; j < 4; j++) {
        int n = n0 + ns + j * 8;
        if (n < N) *(float4*)(A + (size_t)n * FEAT + fg) = a0[j];
    }
}

extern "C" void kernel_launch(void* const* d_in, const int* in_sizes, int n_in,
                              void* d_out, int out_size, void* d_ws, size_t ws_size,
                              hipStream_t stream) {
    const float* X  = (const float*)d_in[0];
    const int*   ei = (const int*)d_in[1];
    const float* Wq = (const float*)d_in[2];
    const float* bq = (const float*)d_in[3];
    const float* Wk = (const float*)d_in[4];
    const float* bk = (const float*)d_in[5];
    const float* Wv = (const float*)d_in[6];
    const float* bv = (const float*)d_in[7];
    const float* Wo = (const float*)d_in[8];
    const float* bo = (const float*)d_in[9];
    float* out = (float*)d_out;

    const int N = in_sizes[0] / FEAT;        // 50000
    const int E = in_sizes[1] / 2;           // 600000
    const int* srcs = ei;
    const int* dsts = ei + E;
    const size_t NF = (size_t)N * FEAT;

    // workspace layout
    float* ws = (float*)d_ws;
    float* WT      = ws;                           // 4*16384
    float* Kb      = WT + 4 * 16384;               // N*FEAT
    float* Vb      = Kb + NF;                      // N*FEAT
    float* Qb      = Vb + NF;                      // N*FEAT (dead after scores; reused for cursor+eid)
    float* scores  = Qb + NF;                      // E*NHEAD
    float* segsum  = scores + (size_t)E * NHEAD;   // N*NHEAD (becomes reciprocal)
    int*   counts  = (int*)(segsum + (size_t)N * NHEAD);  // N
    int*   offsets = counts + N;                   // N
    int*   blocksums = offsets + N;                // 256
    int*   blockoffs = blocksums + 256;            // 256
    int*   cursor  = (int*)Qb;                     // N   (aliases dead Q)
    int*   eid     = cursor + N;                   // E   (aliases dead Q)

    // zero segsum + counts (contiguous)
    hipMemsetAsync(segsum, 0, ((size_t)N * NHEAD + N) * sizeof(float), stream);

    transpose_w_kernel<<<(4 * 16384) / 256, 256, 0, stream>>>(Wq, Wk, Wv, Wo, WT);

    qkv_kernel<<<(N + QKV_NPB - 1) / QKV_NPB, 256, 0, stream>>>(
        X, WT, bq, bk, bv, Qb, Kb, Vb, N);

    int eh_blocks = (E * NHEAD + 255) / 256;
    scores_kernel<<<eh_blocks, 256, 0, stream>>>(srcs, dsts, Qb, Kb, scores, segsum, E);

    recip_kernel<<<(N * NHEAD + 255) / 256, 256, 0, stream>>>(segsum, N * NHEAD);

    int e_blocks = (E + 255) / 256;
    hist_kernel<<<e_blocks, 256, 0, stream>>>(dsts, counts, E);

    int NB = (N + 255) / 256;   // 196 <= 256
    scan1_kernel<<<NB, 256, 0, stream>>>(counts, offsets, blocksums, N);
    scan2_kernel<<<1, 256, 0, stream>>>(blocksums, blockoffs, NB);
    scan3_kernel<<<NB, 256, 0, stream>>>(offsets, blockoffs, cursor, N);

    fill_kernel<<<e_blocks, 256, 0, stream>>>(dsts, cursor, eid, E);

    gather_kernel<<<(N + GATH_WPB - 1) / GATH_WPB, 256, 0, stream>>>(
        offsets, counts, eid, srcs, Vb, scores, segsum, out, N);

    out_kernel<<<(N + QKV_NPB - 1) / QKV_NPB, 256, 0, stream>>>(out, WT + 3 * 16384, bo, N);
}

// Round 3
// 401.026 us; speedup vs baseline: 1.6162x; 1.2655x over previous
//
#include <hip/hip_runtime.h>
#include <hip/hip_bf16.h>

// GAT-style graph attention. N=50000, E=600000, FEAT=128, H=8, D=16.
// R3: bf16 MFMA GEMMs (fp32 accumulate), bf16 Q/K/V/agg to halve cache
//     traffic in scores/gather. CSR-by-dest gather aggregation (R2).

#define FEAT 128
#define NHEAD 8
#define NPAD 50048   // N rounded up to multiple of 64 (MFMA row tiles)

typedef __attribute__((ext_vector_type(8))) short bf16x8;   // 8 bf16 = 4 VGPR
typedef __attribute__((ext_vector_type(4))) float f32x4;

__device__ __forceinline__ unsigned short f2bf(float f) {
    unsigned u = __float_as_uint(f);
    u += 0x7fffu + ((u >> 16) & 1u);      // RTN-even
    return (unsigned short)(u >> 16);
}
__device__ __forceinline__ float bf2f_lo(unsigned u) { return __uint_as_float(u << 16); }
__device__ __forceinline__ float bf2f_hi(unsigned u) { return __uint_as_float(u & 0xffff0000u); }

// ---- convert X (N*FEAT floats) to bf16, 8 elems/thread ----
__global__ __launch_bounds__(256) void convert_x_kernel(
    const float* __restrict__ X, unsigned short* __restrict__ Xb, int total8)
{
    int i = blockIdx.x * 256 + threadIdx.x;
    if (i >= total8) return;
    const float4* xp = (const float4*)X + (size_t)i * 2;
    float4 x0 = xp[0], x1 = xp[1];
    uint4 o;
    o.x = (unsigned)f2bf(x0.x) | ((unsigned)f2bf(x0.y) << 16);
    o.y = (unsigned)f2bf(x0.z) | ((unsigned)f2bf(x0.w) << 16);
    o.z = (unsigned)f2bf(x1.x) | ((unsigned)f2bf(x1.y) << 16);
    o.w = (unsigned)f2bf(x1.z) | ((unsigned)f2bf(x1.w) << 16);
    ((uint4*)Xb)[i] = o;
}

// ---- convert 4 weight matrices (each 128x128) to bf16, row-major copy ----
__global__ __launch_bounds__(256) void convert_w_kernel(
    const float* __restrict__ Wq, const float* __restrict__ Wk,
    const float* __restrict__ Wv, const float* __restrict__ Wo,
    unsigned short* __restrict__ Wb)
{
    int i = blockIdx.x * 256 + threadIdx.x;   // 8192 threads, 8 elems each
    if (i >= 4 * 2048) return;
    int mat = i >> 11, idx = i & 2047;
    const float* W = (mat == 0) ? Wq : (mat == 1) ? Wk : (mat == 2) ? Wv : Wo;
    const float4* xp = (const float4*)W + (size_t)idx * 2;
    float4 x0 = xp[0], x1 = xp[1];
    uint4 o;
    o.x = (unsigned)f2bf(x0.x) | ((unsigned)f2bf(x0.y) << 16);
    o.y = (unsigned)f2bf(x0.z) | ((unsigned)f2bf(x0.w) << 16);
    o.z = (unsigned)f2bf(x1.x) | ((unsigned)f2bf(x1.y) << 16);
    o.w = (unsigned)f2bf(x1.z) | ((unsigned)f2bf(x1.w) << 16);
    ((uint4*)(Wb + (size_t)mat * 16384))[idx] = o;
}

// ---- QKV MFMA GEMM: block=256 (4 waves), 64 rows/block, wave=16 rows ----
// out[n][f] = sum_k Xb[n][k] * W[f][k]  (+bias), for 3 matrices.
// A frag: lane m=lane&15 row, quad=lane>>4, elems k=quad*8+j  -> 16B load
// B frag: col=lane&15 -> W row (f), same k split               -> 16B load
// C/D:    col=lane&15, row=quad*4+reg
__global__ __launch_bounds__(256) void qkv_mfma_kernel(
    const unsigned short* __restrict__ Xb, const unsigned short* __restrict__ Wb,
    const float* __restrict__ bq, const float* __restrict__ bk, const float* __restrict__ bv,
    unsigned short* __restrict__ Q, unsigned short* __restrict__ K,
    unsigned short* __restrict__ V, int N)
{
    const int lane = threadIdx.x & 63;
    const int wave = threadIdx.x >> 6;
    const int m = lane & 15, quad = lane >> 4;
    const int row0 = blockIdx.x * 64 + wave * 16;

    f32x4 acc[3][8];
    #pragma unroll
    for (int mat = 0; mat < 3; mat++)
        #pragma unroll
        for (int ct = 0; ct < 8; ct++) acc[mat][ct] = (f32x4){0.f, 0.f, 0.f, 0.f};

    const unsigned short* arow = Xb + (size_t)(row0 + m) * FEAT + quad * 8;
    #pragma unroll
    for (int kc = 0; kc < 4; kc++) {
        bf16x8 a = *(const bf16x8*)(arow + kc * 32);
        #pragma unroll
        for (int mat = 0; mat < 3; mat++) {
            const unsigned short* wrow = Wb + mat * 16384 + (size_t)m * FEAT + kc * 32 + quad * 8;
            #pragma unroll
            for (int ct = 0; ct < 8; ct++) {
                bf16x8 b = *(const bf16x8*)(wrow + ct * 16 * FEAT);
                acc[mat][ct] = __builtin_amdgcn_mfma_f32_16x16x32_bf16(a, b, acc[mat][ct], 0, 0, 0);
            }
        }
    }

    unsigned short* outp[3] = {Q, K, V};
    const float* bias[3] = {bq, bk, bv};
    #pragma unroll
    for (int mat = 0; mat < 3; mat++) {
        #pragma unroll
        for (int ct = 0; ct < 8; ct++) {
            float bv_ = bias[mat][ct * 16 + m];
            #pragma unroll
            for (int reg = 0; reg < 4; reg++) {
                int row = row0 + quad * 4 + reg;
                if (row < N)
                    outp[mat][(size_t)row * FEAT + ct * 16 + m] = f2bf(acc[mat][ct][reg] + bv_);
            }
        }
    }
}

// ---- fused scores + exp + segment-sum over src (no max pass: |score| small) ----
__global__ __launch_bounds__(256) void scores_kernel(
    const int* __restrict__ srcs, const int* __restrict__ dsts,
    const unsigned short* __restrict__ Q, const unsigned short* __restrict__ K,
    float* __restrict__ scores, float* __restrict__ segsum, int E)
{
    int tid = blockIdx.x * 256 + threadIdx.x;
    if (tid >= E * NHEAD) return;
    int e = tid >> 3, h = tid & 7;
    int s = srcs[e], d = dsts[e];
    const uint4* qp = (const uint4*)(Q + (size_t)s * FEAT + h * 16);
    const uint4* kp = (const uint4*)(K + (size_t)d * FEAT + h * 16);
    uint4 q0 = qp[0], q1 = qp[1];
    uint4 k0 = kp[0], k1 = kp[1];
    float acc = 0.f;
    acc += bf2f_lo(q0.x) * bf2f_lo(k0.x) + bf2f_hi(q0.x) * bf2f_hi(k0.x);
    acc += bf2f_lo(q0.y) * bf2f_lo(k0.y) + bf2f_hi(q0.y) * bf2f_hi(k0.y);
    acc += bf2f_lo(q0.z) * bf2f_lo(k0.z) + bf2f_hi(q0.z) * bf2f_hi(k0.z);
    acc += bf2f_lo(q0.w) * bf2f_lo(k0.w) + bf2f_hi(q0.w) * bf2f_hi(k0.w);
    acc += bf2f_lo(q1.x) * bf2f_lo(k1.x) + bf2f_hi(q1.x) * bf2f_hi(k1.x);
    acc += bf2f_lo(q1.y) * bf2f_lo(k1.y) + bf2f_hi(q1.y) * bf2f_hi(k1.y);
    acc += bf2f_lo(q1.z) * bf2f_lo(k1.z) + bf2f_hi(q1.z) * bf2f_hi(k1.z);
    acc += bf2f_lo(q1.w) * bf2f_lo(k1.w) + bf2f_hi(q1.w) * bf2f_hi(k1.w);
    float w = __expf(acc * 0.25f);
    scores[tid] = w;
    atomicAdd(segsum + (size_t)s * NHEAD + h, w);
}

__global__ __launch_bounds__(256) void recip_kernel(float* __restrict__ segsum, int n)
{
    int i = blockIdx.x * 256 + threadIdx.x;
    if (i < n) segsum[i] = 1.0f / segsum[i];
}

__global__ __launch_bounds__(256) void hist_kernel(
    const int* __restrict__ dsts, int* __restrict__ counts, int E)
{
    int e = blockIdx.x * 256 + threadIdx.x;
    if (e < E) atomicAdd(counts + dsts[e], 1);
}

__global__ __launch_bounds__(256) void scan1_kernel(
    const int* __restrict__ counts, int* __restrict__ offsets,
    int* __restrict__ blocksums, int N)
{
    __shared__ int buf[256];
    int t = threadIdx.x, i = blockIdx.x * 256 + t;
    int v = (i < N) ? counts[i] : 0;
    buf[t] = v; __syncthreads();
    int x = v;
    #pragma unroll
    for (int off = 1; off < 256; off <<= 1) {
        int y = (t >= off) ? buf[t - off] : 0;
        __syncthreads();
        x += y; buf[t] = x;
        __syncthreads();
    }
    if (i < N) offsets[i] = x - v;
    if (t == 255) blocksums[blockIdx.x] = x;
}

__global__ __launch_bounds__(256) void scan2_kernel(
    int* __restrict__ blocksums, int* __restrict__ blockoffs, int NB)
{
    __shared__ int buf[256];
    int t = threadIdx.x;
    int v = (t < NB) ? blocksums[t] : 0;
    buf[t] = v; __syncthreads();
    int x = v;
    #pragma unroll
    for (int off = 1; off < 256; off <<= 1) {
        int y = (t >= off) ? buf[t - off] : 0;
        __syncthreads();
        x += y; buf[t] = x;
        __syncthreads();
    }
    if (t < NB) blockoffs[t] = x - v;
}

__global__ __launch_bounds__(256) void scan3_kernel(
    int* __restrict__ offsets, const int* __restrict__ blockoffs,
    int* __restrict__ cursor, int N)
{
    int i = blockIdx.x * 256 + threadIdx.x;
    if (i < N) {
        int o = offsets[i] + blockoffs[blockIdx.x];
        offsets[i] = o;
        cursor[i] = o;
    }
}

__global__ __launch_bounds__(256) void fill_kernel(
    const int* __restrict__ dsts, int* __restrict__ cursor,
    int* __restrict__ eid, int E)
{
    int e = blockIdx.x * 256 + threadIdx.x;
    if (e < E) {
        int d = dsts[e];
        int pos = atomicAdd(cursor + d, 1);
        eid[pos] = e;
    }
}

// ---- gather-aggregate, one wave per dest node, 2 cols/lane, bf16 V/agg ----
__global__ __launch_bounds__(256) void gather_kernel(
    const int* __restrict__ offsets, const int* __restrict__ counts,
    const int* __restrict__ eid, const int* __restrict__ srcs,
    const unsigned short* __restrict__ V, const float* __restrict__ scores,
    const float* __restrict__ rsegsum, unsigned short* __restrict__ agg, int N)
{
    int node = blockIdx.x * 4 + (threadIdx.x >> 6);
    if (node >= N) return;
    int lane = threadIdx.x & 63;
    int h = lane >> 3;                       // head of cols 2*lane, 2*lane+1
    int start = offsets[node], deg = counts[node];
    float ax = 0.f, ay = 0.f;
    for (int j = 0; j < deg; j++) {
        int e = eid[start + j];
        int s = srcs[e];
        float w = scores[(size_t)e * NHEAD + h] * rsegsum[(size_t)s * NHEAD + h];
        unsigned v = *(const unsigned*)(V + (size_t)s * FEAT + lane * 2);
        ax += w * bf2f_lo(v);
        ay += w * bf2f_hi(v);
    }
    unsigned o = (unsigned)f2bf(ax) | ((unsigned)f2bf(ay) << 16);
    *(unsigned*)(agg + (size_t)node * FEAT + lane * 2) = o;
}

// ---- out MFMA GEMM: d_out[n][f] = sum_k agg[n][k]*Wo[f][k] + bo[f] ----
__global__ __launch_bounds__(256) void out_mfma_kernel(
    const unsigned short* __restrict__ Ab, const unsigned short* __restrict__ Wob,
    const float* __restrict__ bo, float* __restrict__ out, int N)
{
    const int lane = threadIdx.x & 63;
    const int wave = threadIdx.x >> 6;
    const int m = lane & 15, quad = lane >> 4;
    const int row0 = blockIdx.x * 64 + wave * 16;

    f32x4 acc[8];
    #pragma unroll
    for (int ct = 0; ct < 8; ct++) acc[ct] = (f32x4){0.f, 0.f, 0.f, 0.f};

    const unsigned short* arow = Ab + (size_t)(row0 + m) * FEAT + quad * 8;
    #pragma unroll
    for (int kc = 0; kc < 4; kc++) {
        bf16x8 a = *(const bf16x8*)(arow + kc * 32);
        const unsigned short* wrow = Wob + (size_t)m * FEAT + kc * 32 + quad * 8;
        #pragma unroll
        for (int ct = 0; ct < 8; ct++) {
            bf16x8 b = *(const bf16x8*)(wrow + ct * 16 * FEAT);
            acc[ct] = __builtin_amdgcn_mfma_f32_16x16x32_bf16(a, b, acc[ct], 0, 0, 0);
        }
    }
    #pragma unroll
    for (int ct = 0; ct < 8; ct++) {
        float bv_ = bo[ct * 16 + m];
        #pragma unroll
        for (int reg = 0; reg < 4; reg++) {
            int row = row0 + quad * 4 + reg;
            if (row < N)
                out[(size_t)row * FEAT + ct * 16 + m] = acc[ct][reg] + bv_;
        }
    }
}

extern "C" void kernel_launch(void* const* d_in, const int* in_sizes, int n_in,
                              void* d_out, int out_size, void* d_ws, size_t ws_size,
                              hipStream_t stream) {
    const float* X  = (const float*)d_in[0];
    const int*   ei = (const int*)d_in[1];
    const float* Wq = (const float*)d_in[2];
    const float* bq = (const float*)d_in[3];
    const float* Wk = (const float*)d_in[4];
    const float* bk = (const float*)d_in[5];
    const float* Wv = (const float*)d_in[6];
    const float* bv = (const float*)d_in[7];
    const float* Wo = (const float*)d_in[8];
    const float* bo = (const float*)d_in[9];
    float* out = (float*)d_out;

    const int N = in_sizes[0] / FEAT;        // 50000
    const int E = in_sizes[1] / 2;           // 600000
    const int* srcs = ei;
    const int* dsts = ei + E;

    // workspace layout
    char* w = (char*)d_ws;
    unsigned short* Xb = (unsigned short*)w;  w += (size_t)NPAD * FEAT * 2;
    unsigned short* Qb = (unsigned short*)w;  w += (size_t)NPAD * FEAT * 2;
    unsigned short* Kb = (unsigned short*)w;  w += (size_t)NPAD * FEAT * 2;
    unsigned short* Vb = (unsigned short*)w;  w += (size_t)NPAD * FEAT * 2;
    unsigned short* Ab = (unsigned short*)w;  w += (size_t)NPAD * FEAT * 2;
    unsigned short* Wb = (unsigned short*)w;  w += (size_t)4 * 16384 * 2;
    float* scores      = (float*)w;           w += (size_t)E * NHEAD * 4;
    float* segsum      = (float*)w;           w += (size_t)N * NHEAD * 4;
    int* counts        = (int*)w;             w += (size_t)N * 4;
    int* offsets       = (int*)w;             w += (size_t)N * 4;
    int* blocksums     = (int*)w;             w += 256 * 4;
    int* blockoffs     = (int*)w;             w += 256 * 4;
    int* cursor        = (int*)w;             w += (size_t)N * 4;
    int* eid           = (int*)w;             w += (size_t)E * 4;

    // zero segsum + counts (contiguous)
    hipMemsetAsync(segsum, 0, ((size_t)N * NHEAD + N) * sizeof(float), stream);

    convert_w_kernel<<<(4 * 2048 + 255) / 256, 256, 0, stream>>>(Wq, Wk, Wv, Wo, Wb);

    int x8 = N * FEAT / 8;
    convert_x_kernel<<<(x8 + 255) / 256, 256, 0, stream>>>(X, Xb, x8);

    int e_blocks = (E + 255) / 256;
    hist_kernel<<<e_blocks, 256, 0, stream>>>(dsts, counts, E);

    int row_blocks = NPAD / 64;   // 782
    qkv_mfma_kernel<<<row_blocks, 256, 0, stream>>>(Xb, Wb, bq, bk, bv, Qb, Kb, Vb, N);

    int eh_blocks = (E * NHEAD + 255) / 256;
    scores_kernel<<<eh_blocks, 256, 0, stream>>>(srcs, dsts, Qb, Kb, scores, segsum, E);

    recip_kernel<<<(N * NHEAD + 255) / 256, 256, 0, stream>>>(segsum, N * NHEAD);

    int NB = (N + 255) / 256;
    scan1_kernel<<<NB, 256, 0, stream>>>(counts, offsets, blocksums, N);
    scan2_kernel<<<1, 256, 0, stream>>>(blocksums, blockoffs, NB);
    scan3_kernel<<<NB, 256, 0, stream>>>(offsets, blockoffs, cursor, N);

    fill_kernel<<<e_blocks, 256, 0, stream>>>(dsts, cursor, eid, E);

    gather_kernel<<<(N + 3) / 4, 256, 0, stream>>>(
        offsets, counts, eid, srcs, Vb, scores, segsum, Ab, N);

    out_mfma_kernel<<<row_blocks, 256, 0, stream>>>(Ab, Wb + 3 * 16384, bo, out, N);
}